// Round 8
// baseline (65891.321 us; speedup 1.0000x reference)
//
#include <hip/hip_runtime.h>
#include <cmath>

// ============================================================================
// WorldModel RSSM — round 8 (resubmit of rounds 5-7; broker at capacity 4x):
// FULL float64 numerics (conv encoder + embed + recurrence) to match the
// harness's float64 numpy reference exactly in all categorical decisions.
// r1 (fp32) and r4 (f64 phase B) failed with the SAME 0.878 absmax ->
// divergence source is phase A's fp32 summation order.
// Gumbel stays f32 (matches np's f32-preserving log on the f32 uniform).
// PRNG: JAX threefry2x32, partitionable (counter-mode) path.
// ============================================================================

#define PRNG_PARTITIONABLE 1

#define B_   32
#define T_   50
#define AD   6
#define HD   1024
#define NIMG 1600
#define CHUNK 25

// out offsets (floats)
#define OUT_PL 0
#define OUT_QL 1638400
#define OUT_PS 3276800
#define OUT_HS 4915200

__device__ __forceinline__ double elud(double x) { return x > 0.0 ? x : expm1(x); }

__device__ __forceinline__ void tf2x32(unsigned k0, unsigned k1, unsigned& x0, unsigned& x1) {
  unsigned ks2 = k0 ^ k1 ^ 0x1BD11BDAu;
  x0 += k0; x1 += k1;
#define TFR(r) x0 += x1; x1 = ((x1 << (r)) | (x1 >> (32 - (r)))); x1 ^= x0;
  TFR(13) TFR(15) TFR(26) TFR(6)
  x0 += k1; x1 += ks2 + 1u;
  TFR(17) TFR(29) TFR(16) TFR(24)
  x0 += ks2; x1 += k0 + 2u;
  TFR(13) TFR(15) TFR(26) TFR(6)
  x0 += k0; x1 += k1 + 3u;
  TFR(17) TFR(29) TFR(16) TFR(24)
  x0 += k1; x1 += ks2 + 4u;
  TFR(13) TFR(15) TFR(26) TFR(6)
  x0 += ks2; x1 += k0 + 5u;
#undef TFR
}

__device__ __forceinline__ void sample_key(int t, unsigned& o0, unsigned& o1) {
#if PRNG_PARTITIONABLE
  unsigned x0 = 0u, x1 = (unsigned)t;
  tf2x32(0u, 42u, x0, x1);
  o0 = x0; o1 = x1;
#else
  unsigned r[2];
  for (int q = 0; q < 2; ++q) {
    unsigned i = 2u * (unsigned)t + (unsigned)q;
    unsigned x0 = (i < 50u) ? i : i - 50u;
    unsigned x1 = x0 + 50u;
    tf2x32(0u, 42u, x0, x1);
    r[q] = (i < 50u) ? x0 : x1;
  }
  o0 = r[0]; o1 = r[1];
#endif
}

__device__ __forceinline__ unsigned sample_bits(unsigned key0, unsigned key1, unsigned idx) {
#if PRNG_PARTITIONABLE
  unsigned x0 = 0u, x1 = idx;
  tf2x32(key0, key1, x0, x1);
  return x0 ^ x1;
#else
  unsigned x0 = (idx < 16384u) ? idx : idx - 16384u;
  unsigned x1 = x0 + 16384u;
  tf2x32(key0, key1, x0, x1);
  return (idx < 16384u) ? x0 : x1;
#endif
}

// ------------------------------------------------------------ small utilities
__global__ void __launch_bounds__(256) k_transpose(const float* __restrict__ in,
                                                   float* __restrict__ out, int R, int C) {
  int id = blockIdx.x * 256 + threadIdx.x;
  if (id >= R * C) return;
  int c = id / R, r = id % R;
  out[id] = in[r * C + c];
}

__global__ void __launch_bounds__(256) k_init(const float* __restrict__ prev_state,
                                              const float* __restrict__ prev_hidden,
                                              const float* __restrict__ actions,
                                              double* __restrict__ rnn_in,
                                              double* __restrict__ h_ws) {
  int id = blockIdx.x * 256 + threadIdx.x;
  const int n1 = B_ * (HD + AD);  // 32*1030
  if (id < n1) {
    int b = id / 1030, k = id % 1030;
    rnn_in[id] = (double)((k < 1024) ? prev_state[b * 1024 + k]
                                     : actions[(b * T_ + 0) * AD + (k - 1024)]);
  } else {
    int id2 = id - n1;
    if (id2 < B_ * HD) h_ws[id2] = (double)prev_hidden[id2];
  }
}

// ------------------------------------------------------------ conv encoder (f64)
// TIN = float for layer 1 (reads obs), double for f64 intermediates.
template<typename TIN, int CIN, int HIN, int COUT, int PXB, int OCB, int CICH>
__global__ void __launch_bounds__(256) k_conv_d(const TIN* __restrict__ in,
                                                const float* __restrict__ wT,
                                                const float* __restrict__ bias,
                                                double* __restrict__ out) {
  constexpr int HOUT = HIN / 2;
  constexpr int PX   = HOUT * HOUT;
  constexpr int NPXB = (PX + PXB - 1) / PXB;
  constexpr int NOCG = 256 / PXB;
  constexpr int OCA  = OCB / NOCG;

  int n   = blockIdx.x / NPXB;
  int pxb = blockIdx.x % NPXB;
  int oc0 = blockIdx.y * OCB;
  int t   = threadIdx.x;
  int px  = pxb * PXB + (t % PXB);
  int ocg = t / PXB;
  int oy = px / HOUT, ox = px % HOUT;
  int ocb = oc0 + ocg * OCA;

  double acc[OCA];
#pragma unroll
  for (int a = 0; a < OCA; ++a) acc[a] = (double)bias[ocb + a];

  __shared__ TIN ls[CICH * HIN * HIN];
  const TIN* inp = in + (size_t)n * CIN * HIN * HIN;

  for (int cc = 0; cc < CIN; cc += CICH) {
    __syncthreads();
    if constexpr (sizeof(TIN) == 4) {
      const int tot4 = CICH * HIN * HIN / 4;
      const float4* src = (const float4*)(inp + (size_t)cc * HIN * HIN);
      for (int i4 = t; i4 < tot4; i4 += 256) ((float4*)ls)[i4] = src[i4];
    } else {
      const int tot2 = CICH * HIN * HIN / 2;
      const double2* src = (const double2*)(inp + (size_t)cc * HIN * HIN);
      for (int i2 = t; i2 < tot2; i2 += 256) ((double2*)ls)[i2] = src[i2];
    }
    __syncthreads();

    for (int ci = 0; ci < CICH; ++ci) {
#pragma unroll
      for (int ky = 0; ky < 4; ++ky) {
        int iy = 2 * oy - 1 + ky;
        bool vy = (iy >= 0) && (iy < HIN);
#pragma unroll
        for (int kx = 0; kx < 4; ++kx) {
          int ix = 2 * ox - 1 + kx;
          double v = (vy && ix >= 0 && ix < HIN) ? (double)ls[(ci * HIN + iy) * HIN + ix] : 0.0;
          const float* wr = wT + (size_t)((cc + ci) * 16 + ky * 4 + kx) * COUT + ocb;
#pragma unroll
          for (int a = 0; a < OCA; a += 4) {
            float4 w4 = *(const float4*)(wr + a);
            acc[a + 0] += v * (double)w4.x; acc[a + 1] += v * (double)w4.y;
            acc[a + 2] += v * (double)w4.z; acc[a + 3] += v * (double)w4.w;
          }
        }
      }
    }
  }
  double* op = out + ((size_t)n * COUT + ocb) * PX + px;
#pragma unroll
  for (int a = 0; a < OCA; ++a) op[(size_t)a * PX] = elud(acc[a]);
}

// ------------------------------------------------------------ embed GEMM (f64)
// C[M][N] = A[M][K] @ W[N][K]^T + bias ; A f64, W f32
__global__ void __launch_bounds__(256) k_gemm_nt_d(const double* __restrict__ Amat,
                                                   const float* __restrict__ Wmat,
                                                   const float* __restrict__ bias,
                                                   double* __restrict__ Cmat,
                                                   int M, int N, int K) {
  __shared__ double As[16][64];   // 8 KB
  __shared__ double Ws[16][64];   // 8 KB
  int m0 = blockIdx.x * 64, n0 = blockIdx.y * 64;
  int tx = threadIdx.x % 16, ty = threadIdx.x / 16;
  int mi = threadIdx.x >> 2, kq = (threadIdx.x & 3) * 4;
  double acc[4][4] = {};
  for (int k0 = 0; k0 < K; k0 += 16) {
    double a0 = 0., a1 = 0., a2 = 0., a3 = 0.;
    if (m0 + mi < M) {
      const double* ar = Amat + (size_t)(m0 + mi) * K + k0 + kq;
      a0 = ar[0]; a1 = ar[1]; a2 = ar[2]; a3 = ar[3];
    }
    As[kq + 0][mi] = a0; As[kq + 1][mi] = a1; As[kq + 2][mi] = a2; As[kq + 3][mi] = a3;
    float4 w4 = *(const float4*)(Wmat + (size_t)(n0 + mi) * K + k0 + kq);
    Ws[kq + 0][mi] = (double)w4.x; Ws[kq + 1][mi] = (double)w4.y;
    Ws[kq + 2][mi] = (double)w4.z; Ws[kq + 3][mi] = (double)w4.w;
    __syncthreads();
#pragma unroll
    for (int k = 0; k < 16; ++k) {
      double av0 = As[k][ty * 4 + 0], av1 = As[k][ty * 4 + 1];
      double av2 = As[k][ty * 4 + 2], av3 = As[k][ty * 4 + 3];
      double wv0 = Ws[k][tx * 4 + 0], wv1 = Ws[k][tx * 4 + 1];
      double wv2 = Ws[k][tx * 4 + 2], wv3 = Ws[k][tx * 4 + 3];
      acc[0][0] += av0 * wv0; acc[0][1] += av0 * wv1; acc[0][2] += av0 * wv2; acc[0][3] += av0 * wv3;
      acc[1][0] += av1 * wv0; acc[1][1] += av1 * wv1; acc[1][2] += av1 * wv2; acc[1][3] += av1 * wv3;
      acc[2][0] += av2 * wv0; acc[2][1] += av2 * wv1; acc[2][2] += av2 * wv2; acc[2][3] += av2 * wv3;
      acc[3][0] += av3 * wv0; acc[3][1] += av3 * wv1; acc[3][2] += av3 * wv2; acc[3][3] += av3 * wv3;
    }
    __syncthreads();
  }
#pragma unroll
  for (int i = 0; i < 4; ++i) {
    int m = m0 + ty * 4 + i;
    if (m >= M) continue;
#pragma unroll
    for (int j = 0; j < 4; ++j) {
      int nn = n0 + tx * 4 + j;
      Cmat[(size_t)m * N + nn] = acc[i][j] + (double)bias[nn];
    }
  }
}

// ------------------------------------------------------------ recurrence (f64)
// partial[s][b][j] = sum_{k in 64-slice s} X[b][k] * W[j][k]   (X f64, W f32)
struct PMd { const double* X; int ldx; int K; int S; const float* W; double* pb; };

__global__ void __launch_bounds__(256) k_partial_d(PMd ma, PMd mb, int N) {
  PMd m = (blockIdx.z == 0) ? ma : mb;
  int s = blockIdx.y;
  if (s >= m.S) return;
  int j0 = blockIdx.x * 64;
  int k0 = s * 64;
  int kcnt = m.K - k0; if (kcnt > 64) kcnt = 64;

  __shared__ double xs[64][32];    // 16 KB
  __shared__ double wsm[64][64];   // 32 KB
  int t = threadIdx.x;
  {
    int b = t >> 3, kk = (t & 7) * 8;
    const double* xr = m.X + (size_t)b * m.ldx + k0;
#pragma unroll
    for (int q = 0; q < 8; ++q) {
      int k = kk + q;
      xs[k][b] = (k < kcnt) ? xr[k] : 0.0;
    }
  }
  {
    int j = t >> 2, kk = (t & 3) * 16;
    const float* wr = m.W + (size_t)(j0 + j) * m.K + k0;
#pragma unroll
    for (int q = 0; q < 16; ++q) {
      int k = kk + q;
      wsm[k][j] = (k < kcnt) ? (double)wr[k] : 0.0;
    }
  }
  __syncthreads();

  int jg = t & 31, bg = t >> 5;  // 32 j-groups x 2j ; 8 b-groups x 4b
  double acc[4][2] = {};
#pragma unroll 4
  for (int k = 0; k < 64; ++k) {
    double x0 = xs[k][bg * 4 + 0], x1 = xs[k][bg * 4 + 1];
    double x2 = xs[k][bg * 4 + 2], x3 = xs[k][bg * 4 + 3];
    double w0 = wsm[k][jg * 2 + 0], w1 = wsm[k][jg * 2 + 1];
    acc[0][0] += x0 * w0; acc[0][1] += x0 * w1;
    acc[1][0] += x1 * w0; acc[1][1] += x1 * w1;
    acc[2][0] += x2 * w0; acc[2][1] += x2 * w1;
    acc[3][0] += x3 * w0; acc[3][1] += x3 * w1;
  }
  double* pb = m.pb + (size_t)(s * 32 + bg * 4) * N + j0 + jg * 2;
#pragma unroll
  for (int bi = 0; bi < 4; ++bi) {
    pb[(size_t)bi * N + 0] = acc[bi][0];
    pb[(size_t)bi * N + 1] = acc[bi][1];
  }
}

// gates: reduce gi(17)+gh(16) -> GRU -> h ; build q1in; write hs output
__global__ void __launch_bounds__(256) k_gates_d(const double* __restrict__ pgi,
                                                 const double* __restrict__ pgh,
                                                 const float* __restrict__ bih,
                                                 const float* __restrict__ bhh,
                                                 double* __restrict__ h_ws,
                                                 double* __restrict__ q1in,
                                                 const double* __restrict__ emb,
                                                 float* __restrict__ out_hs, int t) {
  int id = blockIdx.x * 256 + threadIdx.x;  // 32768
  int b = id >> 10, j = id & 1023;
  double gr = 0., gz = 0., gn = 0.;
  for (int s = 0; s < 17; ++s) {
    const double* p = pgi + (size_t)(s * 32 + b) * 3072 + j;
    gr += p[0]; gz += p[1024]; gn += p[2048];
  }
  double hr = 0., hz = 0., hn = 0.;
  for (int s = 0; s < 16; ++s) {
    const double* p = pgh + (size_t)(s * 32 + b) * 3072 + j;
    hr += p[0]; hz += p[1024]; hn += p[2048];
  }
  double i_r = gr + (double)bih[j], i_z = gz + (double)bih[1024 + j], i_n = gn + (double)bih[2048 + j];
  double h_r = hr + (double)bhh[j], h_z = hz + (double)bhh[1024 + j], h_n = hn + (double)bhh[2048 + j];
  double r = 1.0 / (1.0 + exp(-(i_r + h_r)));
  double z = 1.0 / (1.0 + exp(-(i_z + h_z)));
  double n = tanh(i_n + r * h_n);
  double h = (1.0 - z) * n + z * h_ws[id];
  h_ws[id] = h;
  q1in[b * 2048 + j] = h;
  q1in[b * 2048 + 1024 + j] = emb[(size_t)(b * T_ + t) * 1024 + j];
  out_hs[(size_t)(b * T_ + t) * 1024 + j] = (float)h;
}

// reduce + bias + LayerNorm + elu (y=0 prior, y=1 posterior)
__global__ void __launch_bounds__(256) k_ln2_d(const double* pbA, int SA, const float* bA,
                                               const float* gA, const float* beA, double* oA,
                                               const double* pbB, int SB, const float* bB,
                                               const float* gB, const float* beB, double* oB) {
  int b = blockIdx.x;
  int isB = blockIdx.y;
  const double* pb = isB ? pbB : pbA;
  int S = isB ? SB : SA;
  const float* bias = isB ? bB : bA;
  const float* g  = isB ? gB : gA;
  const float* be = isB ? beB : beA;
  double* o = isB ? oB : oA;

  int t = threadIdx.x;
  int jb = t * 4;
  double v[4] = {0., 0., 0., 0.};
  for (int s = 0; s < S; ++s) {
    const double* p = pb + (size_t)(s * 32 + b) * 1024 + jb;
#pragma unroll
    for (int q = 0; q < 4; ++q) v[q] += p[q];
  }
#pragma unroll
  for (int q = 0; q < 4; ++q) v[q] += (double)bias[jb + q];

  __shared__ double red[4];
  double sum = v[0] + v[1] + v[2] + v[3];
  for (int off = 32; off; off >>= 1) sum += __shfl_down(sum, off, 64);
  if ((t & 63) == 0) red[t >> 6] = sum;
  __syncthreads();
  double mean = (red[0] + red[1] + red[2] + red[3]) * (1.0 / 1024.0);
  __syncthreads();

  double d0 = v[0] - mean, d1 = v[1] - mean, d2 = v[2] - mean, d3 = v[3] - mean;
  double s2 = d0 * d0 + d1 * d1 + d2 * d2 + d3 * d3;
  for (int off = 32; off; off >>= 1) s2 += __shfl_down(s2, off, 64);
  if ((t & 63) == 0) red[t >> 6] = s2;
  __syncthreads();
  double var = (red[0] + red[1] + red[2] + red[3]) * (1.0 / 1024.0);
  double den = sqrt(var + 1e-5);

  double dd[4] = {d0, d1, d2, d3};
#pragma unroll
  for (int q = 0; q < 4; ++q)
    o[(size_t)b * 1024 + jb + q] = elud(dd[q] / den * (double)g[jb + q] + (double)be[jb + q]);
}

// final: y=0 prior logits ; y=1 posterior logits + gumbel argmax sample
__global__ void __launch_bounds__(1024) k_final_d(const double* __restrict__ pp2,
                                                  const double* __restrict__ pq2,
                                                  const float* __restrict__ pb2,
                                                  const float* __restrict__ qb2,
                                                  const float* __restrict__ actions,
                                                  float* __restrict__ out_pl,
                                                  float* __restrict__ out_ql,
                                                  float* __restrict__ out_ps,
                                                  double* __restrict__ rnn_in, int t) {
  int b = blockIdx.x;
  int j = threadIdx.x;
  if (blockIdx.y == 0) {
    double v = 0.;
    for (int s = 0; s < 16; ++s) v += pp2[(size_t)(s * 32 + b) * 1024 + j];
    out_pl[(size_t)(b * T_ + t) * 1024 + j] = (float)(v + (double)pb2[j]);
  } else {
    double v = 0.;
    for (int s = 0; s < 16; ++s) v += pq2[(size_t)(s * 32 + b) * 1024 + j];
    double ql = v + (double)qb2[j];
    out_ql[(size_t)(b * T_ + t) * 1024 + j] = (float)ql;

    unsigned kk0, kk1;
    sample_key(t, kk0, kk1);
    unsigned bits = sample_bits(kk0, kk1, (unsigned)(b * 1024 + j));
    // uniform & gumbel in f32 (matches jax dtype semantics and np's
    // f32-preserving log), then promote and add to f64 logits.
    float f = __uint_as_float((bits >> 9) | 0x3f800000u) - 1.0f;
    float uf = fmaxf(f, 1.17549435e-38f);
    float gumf = -logf(-logf(uf));
    double val = ql + (double)gumf;

    int d = j & 31;
    double best = val; int bidx = d;
    for (int off = 16; off; off >>= 1) {
      double ov = __shfl_xor(best, off, 32);
      int oi = __shfl_xor(bidx, off, 32);
      if (ov > best || (ov == best && oi < bidx)) { best = ov; bidx = oi; }
    }
    float oh = (d == bidx) ? 1.0f : 0.0f;
    out_ps[(size_t)(b * T_ + t) * 1024 + j] = oh;
    rnn_in[b * 1030 + j] = (double)oh;
    if (j < AD && (t + 1) < T_)
      rnn_in[b * 1030 + 1024 + j] = (double)actions[(size_t)(b * T_ + t + 1) * AD + j];
  }
}

// ============================================================================
extern "C" void kernel_launch(void* const* d_in, const int* in_sizes, int n_in,
                              void* d_out, int out_size, void* d_ws, size_t ws_size,
                              hipStream_t stream) {
  const float* obs        = (const float*)d_in[0];
  const float* actions    = (const float*)d_in[1];
  const float* prev_hid   = (const float*)d_in[2];
  const float* prev_state = (const float*)d_in[3];
  const float* cw1 = (const float*)d_in[4];  const float* cb1 = (const float*)d_in[5];
  const float* cw2 = (const float*)d_in[6];  const float* cb2 = (const float*)d_in[7];
  const float* cw3 = (const float*)d_in[8];  const float* cb3 = (const float*)d_in[9];
  const float* cw4 = (const float*)d_in[10]; const float* cb4 = (const float*)d_in[11];
  const float* ew  = (const float*)d_in[12]; const float* eb  = (const float*)d_in[13];
  const float* wih = (const float*)d_in[14]; const float* whh = (const float*)d_in[15];
  const float* bih = (const float*)d_in[16]; const float* bhh = (const float*)d_in[17];
  const float* pm_w1 = (const float*)d_in[18]; const float* pm_b1 = (const float*)d_in[19];
  const float* pm_g  = (const float*)d_in[20]; const float* pm_be = (const float*)d_in[21];
  const float* pm_w2 = (const float*)d_in[22]; const float* pm_b2 = (const float*)d_in[23];
  const float* qm_w1 = (const float*)d_in[24]; const float* qm_b1 = (const float*)d_in[25];
  const float* qm_g  = (const float*)d_in[26]; const float* qm_be = (const float*)d_in[27];
  const float* qm_w2 = (const float*)d_in[28]; const float* qm_b2 = (const float*)d_in[29];

  float* out_pl = (float*)d_out + OUT_PL;
  float* out_ql = (float*)d_out + OUT_QL;
  float* out_ps = (float*)d_out + OUT_PS;
  float* out_hs = (float*)d_out + OUT_HS;

  // ---- workspace layout ----
  char* wp = (char*)d_ws;
  double* emb = (double*)wp;  wp += sizeof(double) * (size_t)NIMG * 1024;   // 13.1 MB
  float* cw1T = (float*)wp;   wp += sizeof(float) * 48 * 32;
  float* cw2T = (float*)wp;   wp += sizeof(float) * 512 * 64;
  float* cw3T = (float*)wp;   wp += sizeof(float) * 1024 * 128;
  float* cw4T = (float*)wp;   wp += sizeof(float) * 2048 * 256;             // ~2.8 MB
  double* rnn_in = (double*)wp; wp += sizeof(double) * 32 * 1030;
  double* h_ws   = (double*)wp; wp += sizeof(double) * 32 * 1024;
  double* q1in   = (double*)wp; wp += sizeof(double) * 32 * 2048;
  double* a1     = (double*)wp; wp += sizeof(double) * 32 * 1024;
  double* a2     = (double*)wp; wp += sizeof(double) * 32 * 1024;           // ~1.6 MB
  char* sc = wp;  // union scratch (time-aliased), high-water ~26 MB
  // phase A: conv chunk buffers (f64), CHUNK=25
  double* c1b = (double*)sc;
  double* c2b = c1b + (size_t)CHUNK * 32 * 1024;   // 25*32*1024
  double* c3b = c2b + (size_t)CHUNK * 64 * 256;
  double* c4b = c3b + (size_t)CHUNK * 128 * 64;
  // phase B: partial buffers (f64), stage-aliased within each step
  double* pgi = (double*)sc;                         // 17*32*3072
  double* pgh = pgi + (size_t)17 * 32 * 3072;        // 16*32*3072
  double* pp1 = (double*)sc;                         // 16*32*1024
  double* pq1 = pp1 + (size_t)16 * 32 * 1024;        // 32*32*1024
  double* pp2 = (double*)sc;                         // 16*32*1024
  double* pq2 = pp2 + (size_t)16 * 32 * 1024;        // 16*32*1024

  // ---- conv weight transposes ----
  k_transpose<<<6, 256, 0, stream>>>(cw1, cw1T, 32, 48);
  k_transpose<<<128, 256, 0, stream>>>(cw2, cw2T, 64, 512);
  k_transpose<<<512, 256, 0, stream>>>(cw3, cw3T, 128, 1024);
  k_transpose<<<2048, 256, 0, stream>>>(cw4, cw4T, 256, 2048);
  k_init<<<257, 256, 0, stream>>>(prev_state, prev_hid, actions, rnn_in, h_ws);

  // ---- phase A: conv encoder + embed (all f64 accumulate + f64 intermediates)
  for (int cb = 0; cb < NIMG; cb += CHUNK) {
    k_conv_d<float, 3, 64, 32, 256, 32, 3><<<dim3(CHUNK * 4, 1), 256, 0, stream>>>(
        obs + (size_t)cb * 3 * 64 * 64, cw1T, cb1, c1b);
    k_conv_d<double, 32, 32, 64, 256, 16, 8><<<dim3(CHUNK, 4), 256, 0, stream>>>(
        c1b, cw2T, cb2, c2b);
    k_conv_d<double, 64, 16, 128, 64, 64, 32><<<dim3(CHUNK, 2), 256, 0, stream>>>(
        c2b, cw3T, cb3, c3b);
    k_conv_d<double, 128, 8, 256, 16, 256, 64><<<dim3(CHUNK, 1), 256, 0, stream>>>(
        c3b, cw4T, cb4, c4b);
    k_gemm_nt_d<<<dim3((CHUNK + 63) / 64, 16), 256, 0, stream>>>(
        c4b, ew, eb, emb + (size_t)cb * 1024, CHUNK, 1024, 4096);
  }

  // ---- phase B: 50-step recurrence (f64) ----
  for (int t = 0; t < T_; ++t) {
    PMd gi{rnn_in, 1030, 1030, 17, wih, pgi};
    PMd gh{h_ws,   1024, 1024, 16, whh, pgh};
    k_partial_d<<<dim3(48, 17, 2), 256, 0, stream>>>(gi, gh, 3072);
    k_gates_d<<<128, 256, 0, stream>>>(pgi, pgh, bih, bhh, h_ws, q1in, emb, out_hs, t);

    PMd p1{h_ws, 1024, 1024, 16, pm_w1, pp1};
    PMd q1{q1in, 2048, 2048, 32, qm_w1, pq1};
    k_partial_d<<<dim3(16, 32, 2), 256, 0, stream>>>(p1, q1, 1024);
    k_ln2_d<<<dim3(32, 2), 256, 0, stream>>>(pp1, 16, pm_b1, pm_g, pm_be, a1,
                                             pq1, 32, qm_b1, qm_g, qm_be, a2);

    PMd p2{a1, 1024, 1024, 16, pm_w2, pp2};
    PMd q2{a2, 1024, 1024, 16, qm_w2, pq2};
    k_partial_d<<<dim3(16, 16, 2), 256, 0, stream>>>(p2, q2, 1024);
    k_final_d<<<dim3(32, 2), 1024, 0, stream>>>(pp2, pq2, pm_b2, qm_b2, actions,
                                                out_pl, out_ql, out_ps, rnn_in, t);
  }
  (void)in_sizes; (void)n_in; (void)out_size; (void)ws_size;
}